// Round 6
// baseline (223.479 us; speedup 1.0000x reference)
//
#include <hip/hip_runtime.h>
#include <hip/hip_bf16.h>
#include <stdint.h>

// Problem constants: B=8, N=4096, C=512, K=V=512, H=8, hk=hv=64, M = B*N = 32768

typedef __attribute__((ext_vector_type(8))) short short8;
typedef __attribute__((ext_vector_type(4))) float f32x4;
typedef __attribute__((ext_vector_type(4))) unsigned short us4;

__device__ __forceinline__ unsigned short f2bf(float f) {
  union { float f; unsigned u; } v; v.f = f;
  unsigned r = v.u + 0x7FFFu + ((v.u >> 16) & 1u);  // RNE
  return (unsigned short)(r >> 16);
}
__device__ __forceinline__ float bf2f(unsigned short u) {
  union { unsigned u; float f; } v; v.u = ((unsigned)u) << 16;
  return v.f;
}
__device__ __forceinline__ ushort2 pk2(float a, float b) {
  __hip_bfloat162 h = __float22bfloat162_rn(float2{a, b});
  return *reinterpret_cast<ushort2*>(&h);
}
// async global->LDS, 16B per lane; lds base wave-uniform (HW: base + lane*16)
__device__ __forceinline__ void gload16(const void* g, void* l) {
  __builtin_amdgcn_global_load_lds(
      (const __attribute__((address_space(1))) void*)g,
      (__attribute__((address_space(3))) void*)l, 16, 0, 0);
}

// ---------------------------------------------------------------------------
// Transpose + bf16-convert the 4 weight matrices: Wt[w][out][in] = W[in][out]
__global__ void prep_w(const float* __restrict__ Wk, const float* __restrict__ Wq,
                       const float* __restrict__ Wv, const float* __restrict__ Wr,
                       unsigned short* __restrict__ Wt) {
  __shared__ float tile[64][65];
  const int t = threadIdx.x;
  const int bx = blockIdx.x, by = blockIdx.y, w = blockIdx.z;
  const float* W = (w == 0) ? Wk : (w == 1) ? Wq : (w == 2) ? Wv : Wr;
  unsigned short* O = Wt + (size_t)w * 512 * 512;
#pragma unroll
  for (int p = 0; p < 16; ++p) {
    int idx = p * 256 + t; int r = idx >> 6, c = idx & 63;
    tile[r][c] = W[(size_t)(by * 64 + r) * 512 + bx * 64 + c];
  }
  __syncthreads();
#pragma unroll
  for (int p = 0; p < 16; ++p) {
    int idx = p * 256 + t; int r = idx >> 6, c = idx & 63;
    O[(size_t)(bx * 64 + r) * 512 + by * 64 + c] = f2bf(tile[c][r]);
  }
}

// ---------------------------------------------------------------------------
// Streaming pre-pass: xb=bf16(x), yb=bf16(y), xyb=bf16(x+y).
// Flat, 16 elems/thread; all loads issued before any store.
__global__ __launch_bounds__(256) void prep_xy(const float* __restrict__ x, const float* __restrict__ y,
                        unsigned short* __restrict__ xb, unsigned short* __restrict__ yb,
                        unsigned short* __restrict__ xyb) {
  const size_t i = ((size_t)blockIdx.x * 256 + threadIdx.x) * 16;
  float4 a[4], b[4];
#pragma unroll
  for (int q = 0; q < 4; ++q) a[q] = *(const float4*)(x + i + q * 4);
#pragma unroll
  for (int q = 0; q < 4; ++q) b[q] = *(const float4*)(y + i + q * 4);
#pragma unroll
  for (int h = 0; h < 2; ++h) {
    float4 a0 = a[2 * h], a1 = a[2 * h + 1], b0 = b[2 * h], b1 = b[2 * h + 1];
    short8 vx, vy, vs;
    ushort2 p;
    p = pk2(a0.x, a0.y); vx[0] = (short)p.x; vx[1] = (short)p.y;
    p = pk2(a0.z, a0.w); vx[2] = (short)p.x; vx[3] = (short)p.y;
    p = pk2(a1.x, a1.y); vx[4] = (short)p.x; vx[5] = (short)p.y;
    p = pk2(a1.z, a1.w); vx[6] = (short)p.x; vx[7] = (short)p.y;
    p = pk2(b0.x, b0.y); vy[0] = (short)p.x; vy[1] = (short)p.y;
    p = pk2(b0.z, b0.w); vy[2] = (short)p.x; vy[3] = (short)p.y;
    p = pk2(b1.x, b1.y); vy[4] = (short)p.x; vy[5] = (short)p.y;
    p = pk2(b1.z, b1.w); vy[6] = (short)p.x; vy[7] = (short)p.y;
    p = pk2(a0.x + b0.x, a0.y + b0.y); vs[0] = (short)p.x; vs[1] = (short)p.y;
    p = pk2(a0.z + b0.z, a0.w + b0.w); vs[2] = (short)p.x; vs[3] = (short)p.y;
    p = pk2(a1.x + b1.x, a1.y + b1.y); vs[4] = (short)p.x; vs[5] = (short)p.y;
    p = pk2(a1.z + b1.z, a1.w + b1.w); vs[6] = (short)p.x; vs[7] = (short)p.y;
    *(short8*)(xb + i + h * 8) = vx;
    *(short8*)(yb + i + h * 8) = vy;
    *(short8*)(xyb + i + h * 8) = vs;
  }
}

// ---------------------------------------------------------------------------
// Merged projection GEMM (3 sections x 1024 blocks), T2+T4+T5 structure:
// 128x128 tile, BK=64, double-buffered LDS, counted vmcnt, raw s_barrier,
// XOR-swizzled LDS via pre-swizzled global src.
// sec 0: A=xyb -> KeT (exp, transposed) + S atomic row-sums
// sec 1: A=xb  -> VT  (transposed)
// sec 2: A=yb  -> Qp  (fused head-softmax, row-major)
__global__ __launch_bounds__(256) void gemm_proj3(
    const unsigned short* __restrict__ xyb, const unsigned short* __restrict__ xb,
    const unsigned short* __restrict__ yb, const unsigned short* __restrict__ Wt,
    const float* __restrict__ bk, const float* __restrict__ bv, const float* __restrict__ bq,
    unsigned short* __restrict__ KeT, unsigned short* __restrict__ VT,
    unsigned short* __restrict__ Qp, float* __restrict__ S, int sec_off) {
  __shared__ __align__(16) unsigned short As[2][128][64];
  __shared__ __align__(16) unsigned short Bs[2][128][64];
  const int t = threadIdx.x, l = t & 63, w = t >> 6;
  const int lr = l & 15, lg = l >> 4;
  const int wr = w >> 1, wc = w & 1;
  const int sec = (int)(blockIdx.x >> 10) + sec_off;
  const int bid = blockIdx.x & 1023;
  const int swz = (bid & 7) * 128 + (bid >> 3);  // bijective XCD swizzle (1024 % 8 == 0)
  const int tn = swz & 3, tm = swz >> 2;

  const unsigned short* A = (sec == 0) ? xyb : (sec == 1) ? xb : yb;
  const unsigned short* Bbase = Wt + (size_t)((sec == 0) ? 0 : (sec == 1) ? 2 : 1) * 262144;
  const float* bias = (sec == 0) ? bk : (sec == 1) ? bv : bq;

  // staging: lane l covers LDS row (l>>3), phys 16B-unit (l&7); global source
  // pre-swizzled so phys unit p holds logical unit p^(row&7)  [G21]
  const int r0 = w * 8 + (l >> 3);
  const int su = ((l & 7) ^ (l >> 3)) * 8;
  const unsigned short* Ag = A + (size_t)(tm * 128 + r0) * 512 + su;
  const unsigned short* Bg = Bbase + (size_t)(tn * 128 + r0) * 512 + su;

  f32x4 acc[4][4] = {};

#define PSTAGE(buf, kt)                                                        \
  {                                                                            \
    _Pragma("unroll") for (int i = 0; i < 4; ++i) {                            \
      gload16(Ag + (size_t)i * 32 * 512 + (kt) * 64, &As[buf][i * 32 + w * 8][0]); \
      gload16(Bg + (size_t)i * 32 * 512 + (kt) * 64, &Bs[buf][i * 32 + w * 8][0]); \
    }                                                                          \
  }

  PSTAGE(0, 0)
  PSTAGE(1, 1)
  for (int kt = 0; kt < 8; ++kt) {
    const int cur = kt & 1;
    if (kt < 7) { asm volatile("s_waitcnt vmcnt(8)" ::: "memory"); }
    else        { asm volatile("s_waitcnt vmcnt(0)" ::: "memory"); }
    __builtin_amdgcn_s_barrier();
    asm volatile("" ::: "memory");
    __builtin_amdgcn_s_setprio(1);
#pragma unroll
    for (int kk = 0; kk < 2; ++kk) {
      short8 af[4], bf[4];
#pragma unroll
      for (int m = 0; m < 4; ++m)
        af[m] = *(const short8*)&As[cur][wr * 64 + m * 16 + lr][((kk * 4 + lg) ^ (lr & 7)) * 8];
#pragma unroll
      for (int n = 0; n < 4; ++n)
        bf[n] = *(const short8*)&Bs[cur][wc * 64 + n * 16 + lr][((kk * 4 + lg) ^ (lr & 7)) * 8];
#pragma unroll
      for (int m = 0; m < 4; ++m)
#pragma unroll
        for (int n = 0; n < 4; ++n)
          acc[m][n] = __builtin_amdgcn_mfma_f32_16x16x32_bf16(af[m], bf[n], acc[m][n], 0, 0, 0);
    }
    __builtin_amdgcn_s_setprio(0);
    asm volatile("" ::: "memory");
    __builtin_amdgcn_s_barrier();
    asm volatile("" ::: "memory");
    if (kt < 6) PSTAGE(cur, kt + 2)
  }
#undef PSTAGE

  // ---- epilogue ----
  const int c_base = tn * 128 + wc * 64;
  const int r_base = tm * 128 + wr * 64;
  float bv_[4];
#pragma unroll
  for (int n = 0; n < 4; ++n) bv_[n] = bias[c_base + n * 16 + lr];

  if (sec == 2) {
    // fused query-softmax over this wave's 64 cols (= one head), fp32 in-register
#pragma unroll
    for (int m = 0; m < 4; ++m) {
#pragma unroll
      for (int j = 0; j < 4; ++j) {
        float a0 = acc[m][0][j] + bv_[0], a1 = acc[m][1][j] + bv_[1];
        float a2 = acc[m][2][j] + bv_[2], a3 = acc[m][3][j] + bv_[3];
        float mx = fmaxf(fmaxf(a0, a1), fmaxf(a2, a3));
#pragma unroll
        for (int o = 1; o < 16; o <<= 1) mx = fmaxf(mx, __shfl_xor(mx, o));
        float e0 = __expf(a0 - mx), e1 = __expf(a1 - mx);
        float e2 = __expf(a2 - mx), e3 = __expf(a3 - mx);
        float s = e0 + e1 + e2 + e3;
#pragma unroll
        for (int o = 1; o < 16; o <<= 1) s += __shfl_xor(s, o);
        const float rs = 1.0f / s;
        const int row = r_base + m * 16 + lg * 4 + j;
        Qp[(size_t)row * 512 + c_base + 0 * 16 + lr] = f2bf(e0 * rs);
        Qp[(size_t)row * 512 + c_base + 1 * 16 + lr] = f2bf(e1 * rs);
        Qp[(size_t)row * 512 + c_base + 2 * 16 + lr] = f2bf(e2 * rs);
        Qp[(size_t)row * 512 + c_base + 3 * 16 + lr] = f2bf(e3 * rs);
      }
    }
  } else if (sec == 0) {
    const int b = (tm * 128) >> 12;  // tile rows never cross a batch
#pragma unroll
    for (int n = 0; n < 4; ++n) {
      const int col = c_base + n * 16 + lr;
      float srow = 0.f;
#pragma unroll
      for (int m = 0; m < 4; ++m) {
        const int row = r_base + m * 16 + lg * 4;
        const int nl = row & 4095;
        us4 v;
#pragma unroll
        for (int j = 0; j < 4; ++j) {
          float f = __expf(acc[m][n][j] + bv_[n]);
          srow += f;
          v[j] = f2bf(f);
        }
        *(us4*)&KeT[((size_t)(b * 512 + col)) * 4096 + nl] = v;
      }
      // reduce the 64-row partial over the 4 lg groups, one atomic per col
      srow += __shfl_xor(srow, 16);
      srow += __shfl_xor(srow, 32);
      if (lg == 0) atomicAdd(&S[b * 512 + col], srow);
    }
  } else {
    const int b = (tm * 128) >> 12;
#pragma unroll
    for (int n = 0; n < 4; ++n) {
      const int col = c_base + n * 16 + lr;
#pragma unroll
      for (int m = 0; m < 4; ++m) {
        const int row = r_base + m * 16 + lg * 4;
        const int nl = row & 4095;
        us4 v;
#pragma unroll
        for (int j = 0; j < 4; ++j) v[j] = f2bf(acc[m][n][j] + bv_[n]);
        *(us4*)&VT[((size_t)(b * 512 + col)) * 4096 + nl] = v;
      }
    }
  }
}

// ---------------------------------------------------------------------------
// Partial context: D[v][k] = sum_tok VT[v][tok] * KeT[k][tok] over a 1024-token chunk.
__global__ void context_partial(const unsigned short* __restrict__ KeT,
                                const unsigned short* __restrict__ VT,
                                float* __restrict__ cp) {
  const int t = threadIdx.x, l = t & 63, w = t >> 6;
  const int lr = l & 15, lg = l >> 4;
  const int ch = blockIdx.x, h = blockIdx.y, b = blockIdx.z;
  const unsigned short* Kp = KeT + ((size_t)b * 512 + h * 64) * 4096;
  const unsigned short* Vp = VT + ((size_t)b * 512 + h * 64) * 4096;
  const int tok_w = ch * 1024 + w * 256;
  f32x4 acc[4][4] = {};
  for (int s = 0; s < 8; ++s) {
    const int tok = tok_w + s * 32 + lg * 8;
    short8 a[4], kf[4];
#pragma unroll
    for (int m = 0; m < 4; ++m) a[m] = *(const short8*)&Vp[(size_t)(m * 16 + lr) * 4096 + tok];
#pragma unroll
    for (int n = 0; n < 4; ++n) kf[n] = *(const short8*)&Kp[(size_t)(n * 16 + lr) * 4096 + tok];
#pragma unroll
    for (int m = 0; m < 4; ++m)
#pragma unroll
      for (int n = 0; n < 4; ++n)
        acc[m][n] = __builtin_amdgcn_mfma_f32_16x16x32_bf16(a[m], kf[n], acc[m][n], 0, 0, 0);
  }
  __shared__ float red[4][64][64];
#pragma unroll
  for (int m = 0; m < 4; ++m)
#pragma unroll
    for (int n = 0; n < 4; ++n)
#pragma unroll
      for (int j = 0; j < 4; ++j)
        red[w][m * 16 + lg * 4 + j][n * 16 + lr] = acc[m][n][j];
  __syncthreads();
  const int blk = (b * 8 + h) * 4 + ch;
  float* o = cp + (size_t)blk * 4096;
  for (int i = 0; i < 16; ++i) {
    int e = i * 256 + t;
    int v = e >> 6, k = e & 63;
    o[e] = red[0][v][k] + red[1][v][k] + red[2][v][k] + red[3][v][k];
  }
}

// Reduce 4 chunk-partials, normalize by S, store transposed: ctxN[bh][k][v] (bf16)
__global__ void ctx_reduce(const float* __restrict__ cp, const float* __restrict__ S,
                           unsigned short* __restrict__ ctxN) {
  const int bh = blockIdx.x, t = threadIdx.x;
  const float* p = cp + (size_t)bh * 4 * 4096;
  for (int i = 0; i < 16; ++i) {
    int e = i * 256 + t;
    float vsum = p[e] + p[4096 + e] + p[8192 + e] + p[12288 + e];
    int v = e >> 6, k = e & 63;
    ctxN[(size_t)bh * 4096 + k * 64 + v] = f2bf(vsum / S[bh * 64 + k]);
  }
}

// ---------------------------------------------------------------------------
// M[b][c][h*64+k] = sum_v ctxN[b,h][k][v] * Wr[h*64+v][c]   (transposed for final GEMM)
__global__ void ctx_mm(const unsigned short* __restrict__ ctxN, const unsigned short* __restrict__ Wrt,
                       unsigned short* __restrict__ MT) {
  const int t = threadIdx.x, l = t & 63, w = t >> 6;
  const int lr = l & 15, lg = l >> 4;
  const int h = blockIdx.x, b = blockIdx.y;
  const unsigned short* Ap = ctxN + (size_t)(b * 8 + h) * 4096;
  f32x4 acc[4][8] = {};
  const int c0 = w * 128;
#pragma unroll
  for (int kk = 0; kk < 2; ++kk) {
    const int vb = kk * 32 + lg * 8;
    short8 a[4], bfr[8];
#pragma unroll
    for (int m = 0; m < 4; ++m) a[m] = *(const short8*)&Ap[(m * 16 + lr) * 64 + vb];
#pragma unroll
    for (int n = 0; n < 8; ++n) bfr[n] = *(const short8*)&Wrt[(size_t)(c0 + n * 16 + lr) * 512 + h * 64 + vb];
#pragma unroll
    for (int m = 0; m < 4; ++m)
#pragma unroll
      for (int n = 0; n < 8; ++n)
        acc[m][n] = __builtin_amdgcn_mfma_f32_16x16x32_bf16(a[m], bfr[n], acc[m][n], 0, 0, 0);
  }
#pragma unroll
  for (int n = 0; n < 8; ++n) {
    const int c = c0 + n * 16 + lr;
#pragma unroll
    for (int m = 0; m < 4; ++m) {
      const int k = m * 16 + lg * 4;
      us4 v;
#pragma unroll
      for (int j = 0; j < 4; ++j) v[j] = f2bf(acc[m][n][j]);
      *(us4*)&MT[((size_t)b * 512 + c) * 512 + h * 64 + k] = v;
    }
  }
}

// ---------------------------------------------------------------------------
// Final GEMM (T2+T4+T5): out[tok][c] = sum_j Qs[tok][j] * MT[b][c][j] + br[c]  (fp32)
__global__ __launch_bounds__(256) void gemm_final(const unsigned short* __restrict__ Qs,
                           const unsigned short* __restrict__ MT,
                           const float* __restrict__ br, float* __restrict__ out) {
  __shared__ __align__(16) unsigned short As[2][128][64];
  __shared__ __align__(16) unsigned short Bs[2][128][64];
  const int t = threadIdx.x, l = t & 63, w = t >> 6;
  const int lr = l & 15, lg = l >> 4;
  const int wr = w >> 1, wc = w & 1;
  const int bid = blockIdx.x;
  const int swz = (bid & 7) * 128 + (bid >> 3);
  const int tn = swz & 3, tm = swz >> 2;

  const unsigned short* Bbase = MT + (size_t)(tm >> 5) * 262144;
  const int r0 = w * 8 + (l >> 3);
  const int su = ((l & 7) ^ (l >> 3)) * 8;
  const unsigned short* Ag = Qs + (size_t)(tm * 128 + r0) * 512 + su;
  const unsigned short* Bg = Bbase + (size_t)(tn * 128 + r0) * 512 + su;

  f32x4 acc[4][4] = {};

#define PSTAGE(buf, kt)                                                        \
  {                                                                            \
    _Pragma("unroll") for (int i = 0; i < 4; ++i) {                            \
      gload16(Ag + (size_t)i * 32 * 512 + (kt) * 64, &As[buf][i * 32 + w * 8][0]); \
      gload16(Bg + (size_t)i * 32 * 512 + (kt) * 64, &Bs[buf][i * 32 + w * 8][0]); \
    }                                                                          \
  }

  PSTAGE(0, 0)
  PSTAGE(1, 1)
  for (int kt = 0; kt < 8; ++kt) {
    const int cur = kt & 1;
    if (kt < 7) { asm volatile("s_waitcnt vmcnt(8)" ::: "memory"); }
    else        { asm volatile("s_waitcnt vmcnt(0)" ::: "memory"); }
    __builtin_amdgcn_s_barrier();
    asm volatile("" ::: "memory");
    __builtin_amdgcn_s_setprio(1);
#pragma unroll
    for (int kk = 0; kk < 2; ++kk) {
      short8 af[4], bf[4];
#pragma unroll
      for (int m = 0; m < 4; ++m)
        af[m] = *(const short8*)&As[cur][wr * 64 + m * 16 + lr][((kk * 4 + lg) ^ (lr & 7)) * 8];
#pragma unroll
      for (int n = 0; n < 4; ++n)
        bf[n] = *(const short8*)&Bs[cur][wc * 64 + n * 16 + lr][((kk * 4 + lg) ^ (lr & 7)) * 8];
#pragma unroll
      for (int m = 0; m < 4; ++m)
#pragma unroll
        for (int n = 0; n < 4; ++n)
          acc[m][n] = __builtin_amdgcn_mfma_f32_16x16x32_bf16(af[m], bf[n], acc[m][n], 0, 0, 0);
    }
    __builtin_amdgcn_s_setprio(0);
    asm volatile("" ::: "memory");
    __builtin_amdgcn_s_barrier();
    asm volatile("" ::: "memory");
    if (kt < 6) PSTAGE(cur, kt + 2)
  }
#undef PSTAGE

  const int c_base = tn * 128 + wc * 64;
  const int r_base = tm * 128 + wr * 64;
#pragma unroll
  for (int n = 0; n < 4; ++n) {
    const int col = c_base + n * 16 + lr;
    const float bs = br[col];
#pragma unroll
    for (int m = 0; m < 4; ++m) {
      const int row = r_base + m * 16 + lg * 4;
#pragma unroll
      for (int j = 0; j < 4; ++j)
        out[(size_t)(row + j) * 512 + col] = acc[m][n][j] + bs;
    }
  }
}

// ---------------------------------------------------------------------------
extern "C" void kernel_launch(void* const* d_in, const int* in_sizes, int n_in,
                              void* d_out, int out_size, void* d_ws, size_t ws_size,
                              hipStream_t stream) {
  (void)in_sizes; (void)n_in; (void)out_size;
  const float* x  = (const float*)d_in[0];
  const float* y  = (const float*)d_in[1];
  const float* Wk = (const float*)d_in[2];
  const float* bk = (const float*)d_in[3];
  const float* Wq = (const float*)d_in[4];
  const float* bq = (const float*)d_in[5];
  const float* Wv = (const float*)d_in[6];
  const float* bv = (const float*)d_in[7];
  const float* Wr = (const float*)d_in[8];
  const float* br = (const float*)d_in[9];
  float* out = (float*)d_out;

  char* ws = (char*)d_ws;
  unsigned short* Wt   = (unsigned short*)(ws + 0);            //   2 MB: 4x [512][512] bf16
  unsigned short* xb   = (unsigned short*)(ws + 2097152);      //  32 MB: bf16(x)
  unsigned short* yb   = (unsigned short*)(ws + 35651584);     //  32 MB: bf16(y)
  unsigned short* xyb  = (unsigned short*)(ws + 69206016);     //  32 MB: bf16(x+y)
  unsigned short* KeT  = (unsigned short*)(ws + 102760448);    //  32 MB: [B][512][4096] bf16
  unsigned short* VT   = (unsigned short*)(ws + 136314880);    //  32 MB: [B][512][4096] bf16
  float* S             = (float*)(ws + 169869312);             //  16 KB
  float* cp            = (float*)(ws + 169885696);             //   4 MB
  unsigned short* ctxN = (unsigned short*)(ws + 174080000);    //  .5 MB
  unsigned short* MT   = (unsigned short*)(ws + 174604288);    //   4 MB   (ends 178798592)
  unsigned short* QpX  = (unsigned short*)(ws + 178798592);    //  32 MB   (ends 210364416)
  const bool wide = ws_size >= (size_t)210364416;              // fixed per session -> deterministic
  unsigned short* Qp   = wide ? QpX : xyb;                     // fallback aliases xyb (safe: serialized)

  prep_w<<<dim3(8, 8, 4), 256, 0, stream>>>(Wk, Wq, Wv, Wr, Wt);
  prep_xy<<<4096, 256, 0, stream>>>(x, y, xb, yb, xyb);
  hipMemsetAsync(S, 0, 512 * 8 * sizeof(float), stream);
  if (wide) {
    gemm_proj3<<<3072, 256, 0, stream>>>(xyb, xb, yb, Wt, bk, bv, bq, KeT, VT, Qp, S, 0);
  } else {
    gemm_proj3<<<2048, 256, 0, stream>>>(xyb, xb, yb, Wt, bk, bv, bq, KeT, VT, Qp, S, 0);
    gemm_proj3<<<1024, 256, 0, stream>>>(xyb, xb, yb, Wt, bk, bv, bq, KeT, VT, Qp, S, 2);
  }
  context_partial<<<dim3(4, 8, 8), 256, 0, stream>>>(KeT, VT, cp);
  ctx_reduce<<<64, 256, 0, stream>>>(cp, S, ctxN);
  ctx_mm<<<dim3(8, 8), 256, 0, stream>>>(ctxN, Wt + 3 * 262144, MT);
  gemm_final<<<1024, 256, 0, stream>>>(Qp, MT, br, out);
}

// Round 7
// 217.543 us; speedup vs baseline: 1.0273x; 1.0273x over previous
//
#include <hip/hip_runtime.h>
#include <hip/hip_bf16.h>
#include <stdint.h>

// Problem constants: B=8, N=4096, C=512, K=V=512, H=8, hk=hv=64, M = B*N = 32768

typedef __attribute__((ext_vector_type(8))) short short8;
typedef __attribute__((ext_vector_type(4))) float f32x4;
typedef __attribute__((ext_vector_type(4))) unsigned short us4;

__device__ __forceinline__ unsigned short f2bf(float f) {
  union { float f; unsigned u; } v; v.f = f;
  unsigned r = v.u + 0x7FFFu + ((v.u >> 16) & 1u);  // RNE
  return (unsigned short)(r >> 16);
}
__device__ __forceinline__ float bf2f(unsigned short u) {
  union { unsigned u; float f; } v; v.u = ((unsigned)u) << 16;
  return v.f;
}
__device__ __forceinline__ ushort2 pk2(float a, float b) {
  __hip_bfloat162 h = __float22bfloat162_rn(float2{a, b});
  return *reinterpret_cast<ushort2*>(&h);
}
// async global->LDS, 16B per lane; lds base wave-uniform (HW: base + lane*16)
__device__ __forceinline__ void gload16(const void* g, void* l) {
  __builtin_amdgcn_global_load_lds(
      (const __attribute__((address_space(1))) void*)g,
      (__attribute__((address_space(3))) void*)l, 16, 0, 0);
}

// ---------------------------------------------------------------------------
// Transpose + bf16-convert the 4 weight matrices: Wt[w][out][in] = W[in][out]
__global__ void prep_w(const float* __restrict__ Wk, const float* __restrict__ Wq,
                       const float* __restrict__ Wv, const float* __restrict__ Wr,
                       unsigned short* __restrict__ Wt) {
  __shared__ float tile[64][65];
  const int t = threadIdx.x;
  const int bx = blockIdx.x, by = blockIdx.y, w = blockIdx.z;
  const float* W = (w == 0) ? Wk : (w == 1) ? Wq : (w == 2) ? Wv : Wr;
  unsigned short* O = Wt + (size_t)w * 512 * 512;
#pragma unroll
  for (int p = 0; p < 16; ++p) {
    int idx = p * 256 + t; int r = idx >> 6, c = idx & 63;
    tile[r][c] = W[(size_t)(by * 64 + r) * 512 + bx * 64 + c];
  }
  __syncthreads();
#pragma unroll
  for (int p = 0; p < 16; ++p) {
    int idx = p * 256 + t; int r = idx >> 6, c = idx & 63;
    O[(size_t)(bx * 64 + r) * 512 + by * 64 + c] = f2bf(tile[c][r]);
  }
}

// ---------------------------------------------------------------------------
// Streaming pre-pass: xb=bf16(x), yb=bf16(y), xyb=bf16(x+y).
// Flat, 16 elems/thread; all loads issued before any store.
__global__ __launch_bounds__(256) void prep_xy(const float* __restrict__ x, const float* __restrict__ y,
                        unsigned short* __restrict__ xb, unsigned short* __restrict__ yb,
                        unsigned short* __restrict__ xyb) {
  const size_t i = ((size_t)blockIdx.x * 256 + threadIdx.x) * 16;
  float4 a[4], b[4];
#pragma unroll
  for (int q = 0; q < 4; ++q) a[q] = *(const float4*)(x + i + q * 4);
#pragma unroll
  for (int q = 0; q < 4; ++q) b[q] = *(const float4*)(y + i + q * 4);
#pragma unroll
  for (int h = 0; h < 2; ++h) {
    float4 a0 = a[2 * h], a1 = a[2 * h + 1], b0 = b[2 * h], b1 = b[2 * h + 1];
    short8 vx, vy, vs;
    ushort2 p;
    p = pk2(a0.x, a0.y); vx[0] = (short)p.x; vx[1] = (short)p.y;
    p = pk2(a0.z, a0.w); vx[2] = (short)p.x; vx[3] = (short)p.y;
    p = pk2(a1.x, a1.y); vx[4] = (short)p.x; vx[5] = (short)p.y;
    p = pk2(a1.z, a1.w); vx[6] = (short)p.x; vx[7] = (short)p.y;
    p = pk2(b0.x, b0.y); vy[0] = (short)p.x; vy[1] = (short)p.y;
    p = pk2(b0.z, b0.w); vy[2] = (short)p.x; vy[3] = (short)p.y;
    p = pk2(b1.x, b1.y); vy[4] = (short)p.x; vy[5] = (short)p.y;
    p = pk2(b1.z, b1.w); vy[6] = (short)p.x; vy[7] = (short)p.y;
    p = pk2(a0.x + b0.x, a0.y + b0.y); vs[0] = (short)p.x; vs[1] = (short)p.y;
    p = pk2(a0.z + b0.z, a0.w + b0.w); vs[2] = (short)p.x; vs[3] = (short)p.y;
    p = pk2(a1.x + b1.x, a1.y + b1.y); vs[4] = (short)p.x; vs[5] = (short)p.y;
    p = pk2(a1.z + b1.z, a1.w + b1.w); vs[6] = (short)p.x; vs[7] = (short)p.y;
    *(short8*)(xb + i + h * 8) = vx;
    *(short8*)(yb + i + h * 8) = vy;
    *(short8*)(xyb + i + h * 8) = vs;
  }
}

// ---------------------------------------------------------------------------
// bf16 GEMM (R5 skeleton): 128x128 tile, BK=64, double-buffered LDS (64KB),
// counted vmcnt (never 0 mid-loop), raw s_barrier, XOR-swizzled LDS
// (linear gload dest + pre-swizzled global src, swizzled ds_read).
// MODE 0: epilogue exp(), TRANSPOSED out (KeT[b][k][tok]) + S atomic row-sums
// MODE 1: epilogue fused head-softmax (64 ch), row-major bf16 out
// MODE 2: plain, TRANSPOSED out (VT[b][v][tok], bf16)
// MODE 3: final: B = Bmat + batch*512*512, fp32 row-major out + bias
template <int MODE>
__global__ __launch_bounds__(256) void gemm_bf16(const unsigned short* __restrict__ A,
                          const unsigned short* __restrict__ Bmat,
                          const float* __restrict__ bias, void* __restrict__ OutV,
                          float* __restrict__ S) {
  __shared__ __align__(16) unsigned short As[2][128][64];
  __shared__ __align__(16) unsigned short Bs[2][128][64];
  const int t = threadIdx.x, l = t & 63, w = t >> 6;
  const int lr = l & 15, lg = l >> 4;
  const int wr = w >> 1, wc = w & 1;
  const int bid = blockIdx.x;
  const int swz = (bid & 7) * 128 + (bid >> 3);  // bijective XCD swizzle (1024 % 8 == 0)
  const int tn = swz & 3, tm = swz >> 2;

  const unsigned short* Bbase = (MODE == 3) ? (Bmat + (size_t)(tm >> 5) * 262144) : Bmat;
  // staging: lane l covers LDS row (l>>3), phys 16B-unit (l&7); global source
  // pre-swizzled so phys unit p holds logical unit p^(row&7)  [G21]
  const int r0 = w * 8 + (l >> 3);
  const int su = ((l & 7) ^ (l >> 3)) * 8;
  const unsigned short* Ag = A + (size_t)(tm * 128 + r0) * 512 + su;
  const unsigned short* Bg = Bbase + (size_t)(tn * 128 + r0) * 512 + su;

  f32x4 acc[4][4] = {};

#define PSTAGE(buf, kt)                                                        \
  {                                                                            \
    _Pragma("unroll") for (int i = 0; i < 4; ++i) {                            \
      gload16(Ag + (size_t)i * 32 * 512 + (kt) * 64, &As[buf][i * 32 + w * 8][0]); \
      gload16(Bg + (size_t)i * 32 * 512 + (kt) * 64, &Bs[buf][i * 32 + w * 8][0]); \
    }                                                                          \
  }

  PSTAGE(0, 0)
  PSTAGE(1, 1)
  for (int kt = 0; kt < 8; ++kt) {
    const int cur = kt & 1;
    if (kt < 7) { asm volatile("s_waitcnt vmcnt(8)" ::: "memory"); }
    else        { asm volatile("s_waitcnt vmcnt(0)" ::: "memory"); }
    __builtin_amdgcn_s_barrier();
    asm volatile("" ::: "memory");
    __builtin_amdgcn_s_setprio(1);
#pragma unroll
    for (int kk = 0; kk < 2; ++kk) {
      short8 af[4], bf[4];
#pragma unroll
      for (int m = 0; m < 4; ++m)
        af[m] = *(const short8*)&As[cur][wr * 64 + m * 16 + lr][((kk * 4 + lg) ^ (lr & 7)) * 8];
#pragma unroll
      for (int n = 0; n < 4; ++n)
        bf[n] = *(const short8*)&Bs[cur][wc * 64 + n * 16 + lr][((kk * 4 + lg) ^ (lr & 7)) * 8];
#pragma unroll
      for (int m = 0; m < 4; ++m)
#pragma unroll
        for (int n = 0; n < 4; ++n)
          acc[m][n] = __builtin_amdgcn_mfma_f32_16x16x32_bf16(af[m], bf[n], acc[m][n], 0, 0, 0);
    }
    __builtin_amdgcn_s_setprio(0);
    asm volatile("" ::: "memory");
    __builtin_amdgcn_s_barrier();
    asm volatile("" ::: "memory");
    if (kt < 6) PSTAGE(cur, kt + 2)
  }
#undef PSTAGE

  // ---- epilogue ----
  const int c_base = tn * 128 + wc * 64;
  const int r_base = tm * 128 + wr * 64;
  float bv_[4];
#pragma unroll
  for (int n = 0; n < 4; ++n) bv_[n] = bias[c_base + n * 16 + lr];

  if (MODE == 1) {
    unsigned short* Out = (unsigned short*)OutV;
    // fused query-softmax over this wave's 64 cols (= one head), fp32 in-register
#pragma unroll
    for (int m = 0; m < 4; ++m) {
#pragma unroll
      for (int j = 0; j < 4; ++j) {
        float a0 = acc[m][0][j] + bv_[0], a1 = acc[m][1][j] + bv_[1];
        float a2 = acc[m][2][j] + bv_[2], a3 = acc[m][3][j] + bv_[3];
        float mx = fmaxf(fmaxf(a0, a1), fmaxf(a2, a3));
#pragma unroll
        for (int o = 1; o < 16; o <<= 1) mx = fmaxf(mx, __shfl_xor(mx, o));
        float e0 = __expf(a0 - mx), e1 = __expf(a1 - mx);
        float e2 = __expf(a2 - mx), e3 = __expf(a3 - mx);
        float s = e0 + e1 + e2 + e3;
#pragma unroll
        for (int o = 1; o < 16; o <<= 1) s += __shfl_xor(s, o);
        const float rs = 1.0f / s;
        const int row = r_base + m * 16 + lg * 4 + j;
        Out[(size_t)row * 512 + c_base + 0 * 16 + lr] = f2bf(e0 * rs);
        Out[(size_t)row * 512 + c_base + 1 * 16 + lr] = f2bf(e1 * rs);
        Out[(size_t)row * 512 + c_base + 2 * 16 + lr] = f2bf(e2 * rs);
        Out[(size_t)row * 512 + c_base + 3 * 16 + lr] = f2bf(e3 * rs);
      }
    }
  } else if (MODE == 3) {
    float* Out = (float*)OutV;
#pragma unroll
    for (int n = 0; n < 4; ++n) {
      const int col = c_base + n * 16 + lr;
#pragma unroll
      for (int m = 0; m < 4; ++m) {
        const int row = r_base + m * 16 + lg * 4;
#pragma unroll
        for (int j = 0; j < 4; ++j)
          Out[(size_t)(row + j) * 512 + col] = acc[m][n][j] + bv_[n];
      }
    }
  } else if (MODE == 0) {
    unsigned short* Out = (unsigned short*)OutV;
    const int b = (tm * 128) >> 12;  // tile rows never cross a batch
#pragma unroll
    for (int n = 0; n < 4; ++n) {
      const int col = c_base + n * 16 + lr;
      float srow = 0.f;
#pragma unroll
      for (int m = 0; m < 4; ++m) {
        const int row = r_base + m * 16 + lg * 4;
        const int nl = row & 4095;
        us4 v;
#pragma unroll
        for (int j = 0; j < 4; ++j) {
          float f = __expf(acc[m][n][j] + bv_[n]);
          srow += f;
          v[j] = f2bf(f);
        }
        *(us4*)&Out[((size_t)(b * 512 + col)) * 4096 + nl] = v;
      }
      // reduce over the 4 lg groups (lanes differing in bits 4,5), 1 atomic/col/wave
      srow += __shfl_xor(srow, 16);
      srow += __shfl_xor(srow, 32);
      if (lg == 0) atomicAdd(&S[b * 512 + col], srow);
    }
  } else {
    unsigned short* Out = (unsigned short*)OutV;
    const int b = (tm * 128) >> 12;
#pragma unroll
    for (int n = 0; n < 4; ++n) {
      const int col = c_base + n * 16 + lr;
#pragma unroll
      for (int m = 0; m < 4; ++m) {
        const int row = r_base + m * 16 + lg * 4;
        const int nl = row & 4095;
        us4 v;
#pragma unroll
        for (int j = 0; j < 4; ++j) v[j] = f2bf(acc[m][n][j] + bv_[n]);
        *(us4*)&Out[((size_t)(b * 512 + col)) * 4096 + nl] = v;
      }
    }
  }
}

// ---------------------------------------------------------------------------
// Partial context: D[v][k] = sum_tok VT[v][tok] * KeT[k][tok] over a 1024-token chunk.
__global__ void context_partial(const unsigned short* __restrict__ KeT,
                                const unsigned short* __restrict__ VT,
                                float* __restrict__ cp) {
  const int t = threadIdx.x, l = t & 63, w = t >> 6;
  const int lr = l & 15, lg = l >> 4;
  const int ch = blockIdx.x, h = blockIdx.y, b = blockIdx.z;
  const unsigned short* Kp = KeT + ((size_t)b * 512 + h * 64) * 4096;
  const unsigned short* Vp = VT + ((size_t)b * 512 + h * 64) * 4096;
  const int tok_w = ch * 1024 + w * 256;
  f32x4 acc[4][4] = {};
  for (int s = 0; s < 8; ++s) {
    const int tok = tok_w + s * 32 + lg * 8;
    short8 a[4], kf[4];
#pragma unroll
    for (int m = 0; m < 4; ++m) a[m] = *(const short8*)&Vp[(size_t)(m * 16 + lr) * 4096 + tok];
#pragma unroll
    for (int n = 0; n < 4; ++n) kf[n] = *(const short8*)&Kp[(size_t)(n * 16 + lr) * 4096 + tok];
#pragma unroll
    for (int m = 0; m < 4; ++m)
#pragma unroll
      for (int n = 0; n < 4; ++n)
        acc[m][n] = __builtin_amdgcn_mfma_f32_16x16x32_bf16(a[m], kf[n], acc[m][n], 0, 0, 0);
  }
  __shared__ float red[4][64][64];
#pragma unroll
  for (int m = 0; m < 4; ++m)
#pragma unroll
    for (int n = 0; n < 4; ++n)
#pragma unroll
      for (int j = 0; j < 4; ++j)
        red[w][m * 16 + lg * 4 + j][n * 16 + lr] = acc[m][n][j];
  __syncthreads();
  const int blk = (b * 8 + h) * 4 + ch;
  float* o = cp + (size_t)blk * 4096;
  for (int i = 0; i < 16; ++i) {
    int e = i * 256 + t;
    int v = e >> 6, k = e & 63;
    o[e] = red[0][v][k] + red[1][v][k] + red[2][v][k] + red[3][v][k];
  }
}

// Reduce 4 chunk-partials, normalize by S, store transposed: ctxN[bh][k][v] (bf16)
__global__ void ctx_reduce(const float* __restrict__ cp, const float* __restrict__ S,
                           unsigned short* __restrict__ ctxN) {
  const int bh = blockIdx.x, t = threadIdx.x;
  const float* p = cp + (size_t)bh * 4 * 4096;
  for (int i = 0; i < 16; ++i) {
    int e = i * 256 + t;
    float vsum = p[e] + p[4096 + e] + p[8192 + e] + p[12288 + e];
    int v = e >> 6, k = e & 63;
    ctxN[(size_t)bh * 4096 + k * 64 + v] = f2bf(vsum / S[bh * 64 + k]);
  }
}

// ---------------------------------------------------------------------------
// M[b][c][h*64+k] = sum_v ctxN[b,h][k][v] * Wr[h*64+v][c]   (transposed for final GEMM)
__global__ void ctx_mm(const unsigned short* __restrict__ ctxN, const unsigned short* __restrict__ Wrt,
                       unsigned short* __restrict__ MT) {
  const int t = threadIdx.x, l = t & 63, w = t >> 6;
  const int lr = l & 15, lg = l >> 4;
  const int h = blockIdx.x, b = blockIdx.y;
  const unsigned short* Ap = ctxN + (size_t)(b * 8 + h) * 4096;
  f32x4 acc[4][8] = {};
  const int c0 = w * 128;
#pragma unroll
  for (int kk = 0; kk < 2; ++kk) {
    const int vb = kk * 32 + lg * 8;
    short8 a[4], bfr[8];
#pragma unroll
    for (int m = 0; m < 4; ++m) a[m] = *(const short8*)&Ap[(m * 16 + lr) * 64 + vb];
#pragma unroll
    for (int n = 0; n < 8; ++n) bfr[n] = *(const short8*)&Wrt[(size_t)(c0 + n * 16 + lr) * 512 + h * 64 + vb];
#pragma unroll
    for (int m = 0; m < 4; ++m)
#pragma unroll
      for (int n = 0; n < 8; ++n)
        acc[m][n] = __builtin_amdgcn_mfma_f32_16x16x32_bf16(a[m], bfr[n], acc[m][n], 0, 0, 0);
  }
#pragma unroll
  for (int n = 0; n < 8; ++n) {
    const int c = c0 + n * 16 + lr;
#pragma unroll
    for (int m = 0; m < 4; ++m) {
      const int k = m * 16 + lg * 4;
      us4 v;
#pragma unroll
      for (int j = 0; j < 4; ++j) v[j] = f2bf(acc[m][n][j]);
      *(us4*)&MT[((size_t)b * 512 + c) * 512 + h * 64 + k] = v;
    }
  }
}

// ---------------------------------------------------------------------------
extern "C" void kernel_launch(void* const* d_in, const int* in_sizes, int n_in,
                              void* d_out, int out_size, void* d_ws, size_t ws_size,
                              hipStream_t stream) {
  (void)in_sizes; (void)n_in; (void)out_size;
  const float* x  = (const float*)d_in[0];
  const float* y  = (const float*)d_in[1];
  const float* Wk = (const float*)d_in[2];
  const float* bk = (const float*)d_in[3];
  const float* Wq = (const float*)d_in[4];
  const float* bq = (const float*)d_in[5];
  const float* Wv = (const float*)d_in[6];
  const float* bv = (const float*)d_in[7];
  const float* Wr = (const float*)d_in[8];
  const float* br = (const float*)d_in[9];
  float* out = (float*)d_out;

  char* ws = (char*)d_ws;
  unsigned short* Wt   = (unsigned short*)(ws + 0);            //   2 MB: 4x [512][512] bf16
  unsigned short* xb   = (unsigned short*)(ws + 2097152);      //  32 MB: bf16(x)
  unsigned short* yb   = (unsigned short*)(ws + 35651584);     //  32 MB: bf16(y)
  unsigned short* xyb  = (unsigned short*)(ws + 69206016);     //  32 MB: bf16(x+y)
  unsigned short* KeT  = (unsigned short*)(ws + 102760448);    //  32 MB: [B][512][4096] bf16
  unsigned short* VT   = (unsigned short*)(ws + 136314880);    //  32 MB: [B][512][4096] bf16
  float* S             = (float*)(ws + 169869312);             //  16 KB
  float* cp            = (float*)(ws + 169885696);             //   4 MB
  unsigned short* ctxN = (unsigned short*)(ws + 174080000);    //  .5 MB
  unsigned short* MT   = (unsigned short*)(ws + 174604288);    //   4 MB   (ends 178798592)
  unsigned short* Qp   = xyb;                                  // xyb dead after gemm<0>

  prep_w<<<dim3(8, 8, 4), 256, 0, stream>>>(Wk, Wq, Wv, Wr, Wt);
  prep_xy<<<4096, 256, 0, stream>>>(x, y, xb, yb, xyb);
  hipMemsetAsync(S, 0, 512 * 8 * sizeof(float), stream);
  gemm_bf16<0><<<1024, 256, 0, stream>>>(xyb, Wt, bk, KeT, S);
  gemm_bf16<2><<<1024, 256, 0, stream>>>(xb, Wt + 2 * 262144, bv, VT, nullptr);
  gemm_bf16<1><<<1024, 256, 0, stream>>>(yb, Wt + 262144, bq, Qp, nullptr);
  context_partial<<<dim3(4, 8, 8), 256, 0, stream>>>(KeT, VT, cp);
  ctx_reduce<<<64, 256, 0, stream>>>(cp, S, ctxN);
  ctx_mm<<<dim3(8, 8), 256, 0, stream>>>(ctxN, Wt + 3 * 262144, MT);
  gemm_bf16<3><<<1024, 256, 0, stream>>>(Qp, MT, br, out, nullptr);
}